// Round 3
// baseline (257.697 us; speedup 1.0000x reference)
//
#include <hip/hip_runtime.h>
#include <hip/hip_bf16.h>

#define NROWS 32768
#define HH 128
#define ENTN 50000

typedef short bf16x8 __attribute__((ext_vector_type(8)));
typedef float f32x4 __attribute__((ext_vector_type(4)));

// ws byte offsets
#define OFF_PE  0                        // f32 [50000][128][2]  (m,g interleaved)
#define OFF_PEW 51200000                 // f32 [128][256] k-major ent-slice weights
#define OFF_WF  (OFF_PEW + 131072)       // bf16 [8][2][8][64][8] acc-weight frags (4 hi, 4 lo)
#define OFF_PO  (OFF_WF + 131072)        // f32 [5][128][2]  op contrib + bias, interleaved

__device__ __forceinline__ unsigned short f2bf(float x) {
    unsigned u = __float_as_uint(x);
    return (unsigned short)((u + 0x7FFFu + ((u >> 16) & 1u)) >> 16);
}
__device__ __forceinline__ float bf2f(unsigned short h) {
    return __uint_as_float(((unsigned)h) << 16);
}

__device__ __forceinline__ int sw_idx(int k, int r) {   // pe_kernel staging swizzle
    return (k * 64 + r) ^ (((k >> 2) & 7) << 2);
}

// ---------------- prep: PEW, WF, PO, out tail ----------------
__global__ void prep_kernel(const float* __restrict__ op_table,
                            const float* __restrict__ non_table,
                            const float* __restrict__ Wm, const float* __restrict__ bm,
                            const float* __restrict__ Wg, const float* __restrict__ bg,
                            char* __restrict__ ws, float* __restrict__ out) {
    int idx = blockIdx.x * blockDim.x + threadIdx.x;
    float* PEW = (float*)(ws + OFF_PEW);
    unsigned short* WF = (unsigned short*)(ws + OFF_WF);
    float* PO = (float*)(ws + OFF_PO);
    if (idx < 32768) {                       // PEW[k][j] = W*[j][128+k]
        int k = idx >> 8, j = idx & 255;
        float v = (j < 128) ? Wm[j * 384 + 128 + k] : Wg[(j - 128) * 384 + 128 + k];
        PEW[idx] = v;
    } else if (idx < 98304) {                // WF: acc-path weight fragments
        int t2 = idx - 32768;
        int j = t2 & 7;
        int element = t2 >> 3;
        int lane = element & 63;
        int f = (element >> 6) & 7;
        int wc = element >> 9;
        int ct = wc & 1, w = wc >> 1;
        int col = (ct ? 128 : 0) + 16 * w + (lane & 15);
        int krel = (f & 3) * 32 + (lane >> 4) * 8 + j;
        const float* Wrow = (col < 128) ? (Wm + (size_t)col * 384)
                                        : (Wg + (size_t)(col - 128) * 384);
        float x = Wrow[256 + krel];
        unsigned short h = f2bf(x);
        WF[t2] = (f < 4) ? h : f2bf(x - bf2f(h));
    } else if (idx < 99584) {                // PO[o][c][p]
        int t2 = idx - 98304;
        int o = t2 >> 8, jj = t2 & 255;
        const float* Wrow = (jj < 128) ? (Wm + (size_t)jj * 384)
                                       : (Wg + (size_t)(jj - 128) * 384);
        float s = (jj < 128) ? bm[jj] : bg[jj - 128];
        for (int i = 0; i < 128; ++i) s += op_table[o * HH + i] * Wrow[i];
        int c = jj & 127, p = jj >> 7;
        PO[o * 256 + 2 * c + p] = s;
    } else if (idx < 99712) {
        int j = idx - 99584;
        out[(size_t)NROWS * HH + j] = non_table[j];
    }
}

// ---------------- PE[e][c][{m,g}] = ent_table @ PEW ----------------
__global__ __launch_bounds__(512, 2)
void pe_kernel(const float* __restrict__ ent_table, char* __restrict__ wsc) {
    extern __shared__ float lds[];
    float* Ws = lds;           // [128][256]
    float* aT = lds + 32768;   // [128][64] swizzled
    const float* PEW = (const float*)(wsc + OFF_PEW);
    float* PE = (float*)(wsc + OFF_PE);
    int tid = threadIdx.x;
    int e0 = blockIdx.x * 64;

    #pragma unroll
    for (int c = 0; c < 16; ++c) {
        int i = tid + 512 * c;
        reinterpret_cast<float4*>(Ws)[i] = reinterpret_cast<const float4*>(PEW)[i];
    }
    {
        int r = tid >> 3, sub = tid & 7;
        int e = e0 + r;
        if (e < ENTN) {
            const float4* src = (const float4*)(ent_table + (size_t)e * HH + sub * 16);
            #pragma unroll
            for (int i4 = 0; i4 < 4; ++i4) {
                float4 v = src[i4];
                int kb = sub * 16 + i4 * 4;
                aT[sw_idx(kb + 0, r)] = v.x;
                aT[sw_idx(kb + 1, r)] = v.y;
                aT[sw_idx(kb + 2, r)] = v.z;
                aT[sw_idx(kb + 3, r)] = v.w;
            }
        } else {
            #pragma unroll
            for (int i4 = 0; i4 < 16; ++i4) aT[sw_idx(sub * 16 + i4, r)] = 0.f;
        }
    }
    __syncthreads();

    int rg = tid >> 5, cg = tid & 31;
    int r0 = rg * 4, c0 = cg * 4;
    float zm[4][4] = {{0}}, zg[4][4] = {{0}};

    #pragma unroll 4
    for (int k = 0; k < 128; ++k) {
        float4 a  = *(const float4*)(&aT[sw_idx(k, r0)]);
        float4 wm = *(const float4*)(&Ws[(k << 8) + c0]);
        float4 wg = *(const float4*)(&Ws[(k << 8) + 128 + c0]);
        float av[4]  = {a.x, a.y, a.z, a.w};
        float wmv[4] = {wm.x, wm.y, wm.z, wm.w};
        float wgv[4] = {wg.x, wg.y, wg.z, wg.w};
        #pragma unroll
        for (int rr = 0; rr < 4; ++rr)
            #pragma unroll
            for (int cc = 0; cc < 4; ++cc) {
                zm[rr][cc] = fmaf(av[rr], wmv[cc], zm[rr][cc]);
                zg[rr][cc] = fmaf(av[rr], wgv[cc], zg[rr][cc]);
            }
    }
    #pragma unroll
    for (int rr = 0; rr < 4; ++rr) {
        int e2 = e0 + r0 + rr;
        if (e2 < ENTN) {
            float4 w0 = make_float4(zm[rr][0], zg[rr][0], zm[rr][1], zg[rr][1]);
            float4 w1 = make_float4(zm[rr][2], zg[rr][2], zm[rr][3], zg[rr][3]);
            *(float4*)(&PE[(size_t)e2 * 256 + 2 * c0]) = w0;
            *(float4*)(&PE[(size_t)e2 * 256 + 2 * c0 + 4]) = w1;
        }
    }
}

// ---------------- fused 17-step chain: 2 chains/block, double-buffered, 1 barrier/iter ----------------
__global__ __launch_bounds__(512, 2)
void chain_kernel(const float* __restrict__ ent_table,
                  const int* __restrict__ ops_idx,
                  const int* __restrict__ ents_idx,
                  const int* __restrict__ left_idx,
                  const char* __restrict__ ws, float* __restrict__ out) {
    extern __shared__ char smem[];
    char* Abuf = smem;                       // [p][chain][half][32 rows][256B] = 64KB
    float* po2 = (float*)(smem + 65536);     // 1280 f32
    int* eidx  = (int*)(smem + 70656);       // 64*17
    int* oidx  = (int*)(smem + 75008);       // 64*16
    int* lidx  = (int*)(smem + 79104);       // 64

    const float2* PE2 = (const float2*)(ws + OFF_PE);
    const bf16x8* WFp = (const bf16x8*)(ws + OFF_WF);
    const float* POg  = (const float*)(ws + OFF_PO);

    int tid = threadIdx.x;
    int w = tid >> 6, l = tid & 63;
    int lr = l & 15, lg = l >> 4;
    int row0 = blockIdx.x * 64;

    for (int i = tid; i < 64 * 17; i += 512) eidx[i] = ents_idx[row0 * 17 + i];
    for (int i = tid; i < 64 * 16; i += 512) oidx[i] = ops_idx[row0 * 16 + i];
    if (tid < 64) lidx[tid] = left_idx[row0 + tid];
    for (int i = tid; i < 1280; i += 512) po2[i] = POg[i];

    // per-wave weight fragments (hi + lo)
    bf16x8 WH[2][4], WL[2][4];
    #pragma unroll
    for (int ct = 0; ct < 2; ++ct) {
        int base = ((w * 2 + ct) * 8) * 64 + l;
        #pragma unroll
        for (int f = 0; f < 4; ++f) {
            WH[ct][f] = WFp[base + f * 64];
            WL[ct][f] = WFp[base + (4 + f) * 64];
        }
    }

    // init acc0 -> buf p=0, both chains
    {
        int ra = tid >> 3;        // 0..63
        int sub = tid & 7;
        int k0 = sub * 16;
        int e = ents_idx[(row0 + ra) * 17 + 16];
        int ch = ra >> 5, r = ra & 31;
        const float4* src = (const float4*)(ent_table + (size_t)e * HH + k0);
        int byt0 = (ch << 14) + r * 256;
        int sz = ((r >> 2) & 3) << 5;
        #pragma unroll
        for (int h4 = 0; h4 < 2; ++h4) {
            float4 v0 = src[2 * h4], v1 = src[2 * h4 + 1];
            float xv[8] = {v0.x, v0.y, v0.z, v0.w, v1.x, v1.y, v1.z, v1.w};
            unsigned short h8[8], l8[8];
            #pragma unroll
            for (int j = 0; j < 8; ++j) {
                unsigned u = __float_as_uint(xv[j]);
                h8[j] = (unsigned short)(u >> 16);
                float res = xv[j] - __uint_as_float(u & 0xffff0000u);
                l8[j] = (unsigned short)(__float_as_uint(res) >> 16);
            }
            int byt = (byt0 + ((k0 + 8 * h4) << 1)) ^ sz;
            *(bf16x8*)(Abuf + byt) = *(bf16x8*)h8;
            *(bf16x8*)(Abuf + byt + 8192) = *(bf16x8*)l8;
        }
    }
    __syncthreads();

    int cbase = 16 * w + lr;

    for (int t = 0; t < 17; ++t) {
        int tt = 15 - t;
        int p = t & 1;
        int rdbase = p << 15;
        int wrbase = (p ^ 1) << 15;

        // ---- prefetch chain A ----
        float2 peA[2][4], poA[2][4];
        #pragma unroll
        for (int rt = 0; rt < 2; ++rt)
            #pragma unroll
            for (int i = 0; i < 4; ++i) {
                int r2 = 16 * rt + 4 * lg + i;
                int e = (t < 16) ? eidx[r2 * 17 + tt] : lidx[r2];
                int o = (t < 16) ? oidx[r2 * 16 + tt] : 4;
                peA[rt][i] = PE2[(size_t)e * 128 + cbase];
                poA[rt][i] = ((const float2*)po2)[o * 128 + cbase];
            }

        // ---- MFMA chain A ----
        f32x4 CA[2][2];
        #pragma unroll
        for (int rt = 0; rt < 2; ++rt)
            #pragma unroll
            for (int ct = 0; ct < 2; ++ct) CA[rt][ct] = (f32x4){0.f, 0.f, 0.f, 0.f};
        #pragma unroll
        for (int kt = 0; kt < 4; ++kt) {
            bf16x8 AH[2], AL[2];
            #pragma unroll
            for (int rt = 0; rt < 2; ++rt) {
                int r = 16 * rt + lr;
                int byt = (rdbase + r * 256 + ((kt * 32 + lg * 8) << 1)) ^ (((r >> 2) & 3) << 5);
                AH[rt] = *(const bf16x8*)(Abuf + byt);
                AL[rt] = *(const bf16x8*)(Abuf + byt + 8192);
            }
            #pragma unroll
            for (int rt = 0; rt < 2; ++rt)
                #pragma unroll
                for (int ct = 0; ct < 2; ++ct) {
                    CA[rt][ct] = __builtin_amdgcn_mfma_f32_16x16x32_bf16(AH[rt], WH[ct][kt], CA[rt][ct], 0, 0, 0);
                    CA[rt][ct] = __builtin_amdgcn_mfma_f32_16x16x32_bf16(AL[rt], WH[ct][kt], CA[rt][ct], 0, 0, 0);
                    CA[rt][ct] = __builtin_amdgcn_mfma_f32_16x16x32_bf16(AH[rt], WL[ct][kt], CA[rt][ct], 0, 0, 0);
                }
        }

        // ---- prefetch chain B ----
        float2 peB[2][4], poB[2][4];
        #pragma unroll
        for (int rt = 0; rt < 2; ++rt)
            #pragma unroll
            for (int i = 0; i < 4; ++i) {
                int r2b = 32 + 16 * rt + 4 * lg + i;
                int e = (t < 16) ? eidx[r2b * 17 + tt] : lidx[r2b];
                int o = (t < 16) ? oidx[r2b * 16 + tt] : 4;
                peB[rt][i] = PE2[(size_t)e * 128 + cbase];
                poB[rt][i] = ((const float2*)po2)[o * 128 + cbase];
            }

        // ---- MFMA chain B ----
        f32x4 CB[2][2];
        #pragma unroll
        for (int rt = 0; rt < 2; ++rt)
            #pragma unroll
            for (int ct = 0; ct < 2; ++ct) CB[rt][ct] = (f32x4){0.f, 0.f, 0.f, 0.f};
        #pragma unroll
        for (int kt = 0; kt < 4; ++kt) {
            bf16x8 AH[2], AL[2];
            #pragma unroll
            for (int rt = 0; rt < 2; ++rt) {
                int r = 16 * rt + lr;
                int byt = (rdbase + 16384 + r * 256 + ((kt * 32 + lg * 8) << 1)) ^ (((r >> 2) & 3) << 5);
                AH[rt] = *(const bf16x8*)(Abuf + byt);
                AL[rt] = *(const bf16x8*)(Abuf + byt + 8192);
            }
            #pragma unroll
            for (int rt = 0; rt < 2; ++rt)
                #pragma unroll
                for (int ct = 0; ct < 2; ++ct) {
                    CB[rt][ct] = __builtin_amdgcn_mfma_f32_16x16x32_bf16(AH[rt], WH[ct][kt], CB[rt][ct], 0, 0, 0);
                    CB[rt][ct] = __builtin_amdgcn_mfma_f32_16x16x32_bf16(AL[rt], WH[ct][kt], CB[rt][ct], 0, 0, 0);
                    CB[rt][ct] = __builtin_amdgcn_mfma_f32_16x16x32_bf16(AH[rt], WL[ct][kt], CB[rt][ct], 0, 0, 0);
                }
        }

        // ---- act + write chain A ----
        #pragma unroll
        for (int rt = 0; rt < 2; ++rt)
            #pragma unroll
            for (int i = 0; i < 4; ++i) {
                int r2 = 16 * rt + 4 * lg + i;
                float m = CA[rt][0][i] + peA[rt][i].x + poA[rt][i].x;
                float g = CA[rt][1][i] + peA[rt][i].y + poA[rt][i].y;
                float e1 = __expf(2.f * m);
                float e2 = __expf(-g);
                float an = (e1 - 1.f) * __builtin_amdgcn_rcpf((e1 + 1.f) * (1.f + e2));
                if (t < 16) {
                    unsigned u = __float_as_uint(an);
                    float res = an - __uint_as_float(u & 0xffff0000u);
                    int byt = (wrbase + r2 * 256 + (cbase << 1)) ^ (((r2 >> 2) & 3) << 5);
                    *(unsigned short*)(Abuf + byt) = (unsigned short)(u >> 16);
                    *(unsigned short*)(Abuf + byt + 8192) = (unsigned short)(__float_as_uint(res) >> 16);
                } else {
                    out[(size_t)(row0 + r2) * HH + cbase] = an;
                }
            }

        // ---- act + write chain B ----
        #pragma unroll
        for (int rt = 0; rt < 2; ++rt)
            #pragma unroll
            for (int i = 0; i < 4; ++i) {
                int r2 = 16 * rt + 4 * lg + i;
                float m = CB[rt][0][i] + peB[rt][i].x + poB[rt][i].x;
                float g = CB[rt][1][i] + peB[rt][i].y + poB[rt][i].y;
                float e1 = __expf(2.f * m);
                float e2 = __expf(-g);
                float an = (e1 - 1.f) * __builtin_amdgcn_rcpf((e1 + 1.f) * (1.f + e2));
                if (t < 16) {
                    unsigned u = __float_as_uint(an);
                    float res = an - __uint_as_float(u & 0xffff0000u);
                    int byt = (wrbase + 16384 + r2 * 256 + (cbase << 1)) ^ (((r2 >> 2) & 3) << 5);
                    *(unsigned short*)(Abuf + byt) = (unsigned short)(u >> 16);
                    *(unsigned short*)(Abuf + byt + 8192) = (unsigned short)(__float_as_uint(res) >> 16);
                } else {
                    out[(size_t)(row0 + 32 + r2) * HH + cbase] = an;
                }
            }

        __syncthreads();
    }
}

extern "C" void kernel_launch(void* const* d_in, const int* in_sizes, int n_in,
                              void* d_out, int out_size, void* d_ws, size_t ws_size,
                              hipStream_t stream) {
    const float* ent_table = (const float*)d_in[0];
    const float* op_table  = (const float*)d_in[1];
    const float* non_table = (const float*)d_in[2];
    const float* Wm        = (const float*)d_in[3];
    const float* bm        = (const float*)d_in[4];
    const float* Wg        = (const float*)d_in[5];
    const float* bg        = (const float*)d_in[6];
    const int* ops_idx     = (const int*)d_in[7];
    const int* ents_idx    = (const int*)d_in[8];
    const int* left_idx    = (const int*)d_in[9];
    float* out = (float*)d_out;
    char* ws = (char*)d_ws;

    prep_kernel<<<390, 256, 0, stream>>>(op_table, non_table, Wm, bm, Wg, bg, ws, out);
    pe_kernel<<<782, 512, 163840, stream>>>(ent_table, ws);
    chain_kernel<<<NROWS / 64, 512, 79360, stream>>>(ent_table, ops_idx, ents_idx,
                                                     left_idx, ws, out);
}

// Round 6
// 119.238 us; speedup vs baseline: 2.1612x; 2.1612x over previous
//
#include <hip/hip_runtime.h>
#include <hip/hip_bf16.h>

#define NROWS 32768
#define HH 128
#define ENTN 50000

typedef _Float16 f16x8 __attribute__((ext_vector_type(8)));
typedef float f32x4 __attribute__((ext_vector_type(4)));

// ws byte offsets (WF and PEF are each 32768 f16 = 65536 BYTES)
#define OFF_PEB 0                       // u32 [50000][128] packed {f16 m | f16 g<<16}
#define OFF_EB  25600000                // f16 [50000][128]
#define OFF_WF  38400000                // f16 [8w][2ct][4kt][64][8] acc-weight frags
#define OFF_PEF (OFF_WF + 65536)        // f16 [16ct][4kt][64][8] ent-weight frags
#define OFF_PO  (OFF_PEF + 65536)       // f32 [5][128][2]

__device__ __forceinline__ float h2f(unsigned u) {
    unsigned short s = (unsigned short)u;
    _Float16 h;
    __builtin_memcpy(&h, &s, 2);
    return (float)h;
}
__device__ __forceinline__ unsigned short f2h(float x) {
    _Float16 h = (_Float16)x;
    unsigned short s;
    __builtin_memcpy(&s, &h, 2);
    return s;
}

// ---------------- prep: EB, WF, PEF, PO, out tail ----------------
// branch bounds are ELEMENT counts: EB 800000 thr, WF 32768, PEF 32768, PO 1280, tail 128
__global__ void prep_kernel(const float* __restrict__ ent_table,
                            const float* __restrict__ op_table,
                            const float* __restrict__ non_table,
                            const float* __restrict__ Wm, const float* __restrict__ bm,
                            const float* __restrict__ Wg, const float* __restrict__ bg,
                            char* __restrict__ ws, float* __restrict__ out) {
    int idx = blockIdx.x * blockDim.x + threadIdx.x;
    if (idx < 800000) {                          // EB: ent_table -> f16, 8 elems/thread
        _Float16* EB = (_Float16*)(ws + OFF_EB);
        int base = idx * 8;
        const float4* s = (const float4*)(ent_table + base);
        float4 v0 = s[0], v1 = s[1];
        float xv[8] = {v0.x, v0.y, v0.z, v0.w, v1.x, v1.y, v1.z, v1.w};
        _Float16 h8[8];
        #pragma unroll
        for (int j = 0; j < 8; ++j) h8[j] = (_Float16)xv[j];
        *(f16x8*)(EB + base) = *(f16x8*)h8;
    } else if (idx < 832768) {                   // WF: acc-path weight frags (32768 f16)
        int e = idx - 800000;
        int j = e & 7, l = (e >> 3) & 63, kt = (e >> 9) & 3, ct = (e >> 11) & 1, w = e >> 12;
        int col = (ct ? 128 : 0) + 16 * w + (l & 15);
        int k = kt * 32 + (l >> 4) * 8 + j;
        const float* Wrow = (col < 128) ? (Wm + (size_t)col * 384)
                                        : (Wg + (size_t)(col - 128) * 384);
        ((_Float16*)(ws + OFF_WF))[e] = (_Float16)Wrow[256 + k];
    } else if (idx < 865536) {                   // PEF: ent-path weight frags (32768 f16)
        int e = idx - 832768;
        int j = e & 7, l = (e >> 3) & 63, kt = (e >> 9) & 3, ct = e >> 11;
        int col = 16 * ct + (l & 15);
        int k = kt * 32 + (l >> 4) * 8 + j;
        const float* Wrow = (col < 128) ? (Wm + (size_t)col * 384)
                                        : (Wg + (size_t)(col - 128) * 384);
        ((_Float16*)(ws + OFF_PEF))[e] = (_Float16)Wrow[128 + k];
    } else if (idx < 866816) {                   // PO[o][c][{m,g}] f32
        int e = idx - 865536;
        int o = e >> 8, jj = e & 255;
        const float* Wrow = (jj < 128) ? (Wm + (size_t)jj * 384)
                                       : (Wg + (size_t)(jj - 128) * 384);
        float s = (jj < 128) ? bm[jj] : bg[jj - 128];
        for (int i = 0; i < 128; ++i) s += op_table[o * HH + i] * Wrow[i];
        int c = jj & 127, p = jj >> 7;
        ((float*)(ws + OFF_PO))[o * 256 + 2 * c + p] = s;
    } else if (idx < 866944) {
        int j = idx - 866816;
        out[(size_t)NROWS * HH + j] = non_table[j];
    }
}

// ---------------- PEB = pack_f16(EB @ PEW)  via MFMA ----------------
__global__ __launch_bounds__(256, 4)
void pe_kernel(char* __restrict__ ws) {
    const _Float16* EB = (const _Float16*)(ws + OFF_EB);
    const f16x8* PEF = (const f16x8*)(ws + OFF_PEF);
    unsigned* PEB = (unsigned*)(ws + OFF_PEB);
    int tid = threadIdx.x, w = tid >> 6, l = tid & 63, lr = l & 15, lg = l >> 4;
    int e0 = blockIdx.x * 32;

    f16x8 WB[4][4];
    #pragma unroll
    for (int u = 0; u < 4; ++u) {
        int ct = (u < 2) ? (2 * w + u) : (8 + 2 * w + (u - 2));
        #pragma unroll
        for (int kt = 0; kt < 4; ++kt) WB[u][kt] = PEF[(ct * 4 + kt) * 64 + l];
    }

    f32x4 C[2][4];
    #pragma unroll
    for (int rt = 0; rt < 2; ++rt)
        #pragma unroll
        for (int u = 0; u < 4; ++u) C[rt][u] = (f32x4){0.f, 0.f, 0.f, 0.f};

    #pragma unroll
    for (int kt = 0; kt < 4; ++kt) {
        f16x8 A[2];
        #pragma unroll
        for (int rt = 0; rt < 2; ++rt) {
            int e = e0 + 16 * rt + lr;
            if (e >= ENTN) e = ENTN - 1;
            A[rt] = *(const f16x8*)(EB + (size_t)e * HH + kt * 32 + lg * 8);
        }
        #pragma unroll
        for (int rt = 0; rt < 2; ++rt)
            #pragma unroll
            for (int u = 0; u < 4; ++u)
                C[rt][u] = __builtin_amdgcn_mfma_f32_16x16x32_f16(A[rt], WB[u][kt], C[rt][u], 0, 0, 0);
    }

    #pragma unroll
    for (int rt = 0; rt < 2; ++rt)
        #pragma unroll
        for (int u2 = 0; u2 < 2; ++u2)
            #pragma unroll
            for (int i = 0; i < 4; ++i) {
                int row = e0 + 16 * rt + 4 * lg + i;
                if (row < ENTN) {
                    unsigned pack = (unsigned)f2h(C[rt][u2][i])
                                  | ((unsigned)f2h(C[rt][2 + u2][i]) << 16);
                    PEB[(size_t)row * HH + 32 * w + 16 * u2 + lr] = pack;
                }
            }
}

// ---------------- fused 17-step chain: f16 acc, dual-buffer, 1 barrier/step ----------------
__global__ __launch_bounds__(512, 4)
void chain_kernel(const float* __restrict__ ent_table,
                  const int* __restrict__ ops_idx,
                  const int* __restrict__ ents_idx,
                  const int* __restrict__ left_idx,
                  const char* __restrict__ ws, float* __restrict__ out) {
    __shared__ char Abuf[32768];       // [2p][2ch][32r][256B], XOR-swizzled (r&15)<<4
    __shared__ unsigned eo[64 * 17];   // e | (o<<16), step-ordered

    const unsigned* PEB = (const unsigned*)(ws + OFF_PEB);
    const f16x8* WFp = (const f16x8*)(ws + OFF_WF);
    const float2* PO2 = (const float2*)(ws + OFF_PO);

    int tid = threadIdx.x, w = tid >> 6, l = tid & 63, lr = l & 15, lg = l >> 4;
    int row0 = blockIdx.x * 64;
    int cbase = 16 * w + lr;

    for (int i = tid; i < 64 * 17; i += 512) {
        int r = i / 17, t = i % 17;
        unsigned e, o;
        if (t < 16) {
            e = ents_idx[(row0 + r) * 17 + 15 - t];
            o = ops_idx[(row0 + r) * 16 + 15 - t];
        } else {
            e = left_idx[row0 + r];
            o = 4;
        }
        eo[i] = e | (o << 16);
    }

    float2 po0 = PO2[cbase], po1 = PO2[128 + cbase], po2v = PO2[256 + cbase],
           po3 = PO2[384 + cbase], po4 = PO2[512 + cbase];

    f16x8 WH[2][4];
    #pragma unroll
    for (int ct = 0; ct < 2; ++ct)
        #pragma unroll
        for (int f = 0; f < 4; ++f) WH[ct][f] = WFp[((w * 2 + ct) * 4 + f) * 64 + l];

    {   // acc0 init -> p=0
        int r = tid >> 3, sub = tid & 7;
        int e = ents_idx[(row0 + r) * 17 + 16];
        int ch = r >> 5, rr = r & 31;
        const float4* src = (const float4*)(ent_table + (size_t)e * HH + sub * 16);
        int byt0 = ch * 8192 + rr * 256 + sub * 32;
        int sz = (rr & 15) << 4;
        #pragma unroll
        for (int h = 0; h < 2; ++h) {
            float4 v0 = src[2 * h], v1 = src[2 * h + 1];
            float xv[8] = {v0.x, v0.y, v0.z, v0.w, v1.x, v1.y, v1.z, v1.w};
            _Float16 h8[8];
            #pragma unroll
            for (int j = 0; j < 8; ++j) h8[j] = (_Float16)xv[j];
            *(f16x8*)(Abuf + ((byt0 + 16 * h) ^ sz)) = *(f16x8*)h8;
        }
    }
    __syncthreads();

    int szl = lr << 4;   // read swizzle: (16rt+lr)&15 = lr

    for (int t = 0; t < 17; ++t) {
        int rd = (t & 1) * 16384, wr = rd ^ 16384;

        // prefetch both chains' pe/o
        unsigned peA[2][4], peB[2][4];
        int oA[2][4], oB[2][4];
        #pragma unroll
        for (int rt = 0; rt < 2; ++rt)
            #pragma unroll
            for (int i = 0; i < 4; ++i) {
                int r2 = 16 * rt + 4 * lg + i;
                unsigned v = eo[r2 * 17 + t];
                peA[rt][i] = PEB[(size_t)(v & 0xFFFFu) * HH + cbase];
                oA[rt][i] = v >> 16;
                unsigned vb = eo[(32 + r2) * 17 + t];
                peB[rt][i] = PEB[(size_t)(vb & 0xFFFFu) * HH + cbase];
                oB[rt][i] = vb >> 16;
            }

        f32x4 C[2][2];

        // ---- chain A ----
        #pragma unroll
        for (int rt = 0; rt < 2; ++rt)
            #pragma unroll
            for (int ct = 0; ct < 2; ++ct) C[rt][ct] = (f32x4){0.f, 0.f, 0.f, 0.f};
        #pragma unroll
        for (int kt = 0; kt < 4; ++kt) {
            f16x8 A[2];
            #pragma unroll
            for (int rt = 0; rt < 2; ++rt)
                A[rt] = *(const f16x8*)(Abuf + ((rd + rt * 4096 + lr * 256 + kt * 64 + lg * 16) ^ szl));
            #pragma unroll
            for (int rt = 0; rt < 2; ++rt)
                #pragma unroll
                for (int ct = 0; ct < 2; ++ct)
                    C[rt][ct] = __builtin_amdgcn_mfma_f32_16x16x32_f16(A[rt], WH[ct][kt], C[rt][ct], 0, 0, 0);
        }
        #pragma unroll
        for (int rt = 0; rt < 2; ++rt)
            #pragma unroll
            for (int i = 0; i < 4; ++i) {
                int r2 = 16 * rt + 4 * lg + i;
                float2 pp;
                if (t < 16) {
                    int o = oA[rt][i];
                    pp = (o & 2) ? ((o & 1) ? po3 : po2v) : ((o & 1) ? po1 : po0);
                } else pp = po4;
                unsigned pv = peA[rt][i];
                float m = C[rt][0][i] + h2f(pv & 0xFFFFu) + pp.x;
                float g = C[rt][1][i] + h2f(pv >> 16) + pp.y;
                float e1 = __expf(2.f * m), e2 = __expf(-g);
                float an = (e1 - 1.f) * __builtin_amdgcn_rcpf((e1 + 1.f) * (1.f + e2));
                if (t < 16) {
                    unsigned short hv = f2h(an);
                    *(unsigned short*)(Abuf + ((wr + r2 * 256 + cbase * 2) ^ ((r2 & 15) << 4))) = hv;
                } else {
                    out[(size_t)(row0 + r2) * HH + cbase] = an;
                }
            }

        // ---- chain B ----
        #pragma unroll
        for (int rt = 0; rt < 2; ++rt)
            #pragma unroll
            for (int ct = 0; ct < 2; ++ct) C[rt][ct] = (f32x4){0.f, 0.f, 0.f, 0.f};
        #pragma unroll
        for (int kt = 0; kt < 4; ++kt) {
            f16x8 A[2];
            #pragma unroll
            for (int rt = 0; rt < 2; ++rt)
                A[rt] = *(const f16x8*)(Abuf + ((rd + 8192 + rt * 4096 + lr * 256 + kt * 64 + lg * 16) ^ szl));
            #pragma unroll
            for (int rt = 0; rt < 2; ++rt)
                #pragma unroll
                for (int ct = 0; ct < 2; ++ct)
                    C[rt][ct] = __builtin_amdgcn_mfma_f32_16x16x32_f16(A[rt], WH[ct][kt], C[rt][ct], 0, 0, 0);
        }
        #pragma unroll
        for (int rt = 0; rt < 2; ++rt)
            #pragma unroll
            for (int i = 0; i < 4; ++i) {
                int r2 = 16 * rt + 4 * lg + i;
                float2 pp;
                if (t < 16) {
                    int o = oB[rt][i];
                    pp = (o & 2) ? ((o & 1) ? po3 : po2v) : ((o & 1) ? po1 : po0);
                } else pp = po4;
                unsigned pv = peB[rt][i];
                float m = C[rt][0][i] + h2f(pv & 0xFFFFu) + pp.x;
                float g = C[rt][1][i] + h2f(pv >> 16) + pp.y;
                float e1 = __expf(2.f * m), e2 = __expf(-g);
                float an = (e1 - 1.f) * __builtin_amdgcn_rcpf((e1 + 1.f) * (1.f + e2));
                if (t < 16) {
                    unsigned short hv = f2h(an);
                    *(unsigned short*)(Abuf + ((wr + 8192 + r2 * 256 + cbase * 2) ^ ((r2 & 15) << 4))) = hv;
                } else {
                    out[(size_t)(row0 + 32 + r2) * HH + cbase] = an;
                }
            }

        __syncthreads();
    }
}

extern "C" void kernel_launch(void* const* d_in, const int* in_sizes, int n_in,
                              void* d_out, int out_size, void* d_ws, size_t ws_size,
                              hipStream_t stream) {
    const float* ent_table = (const float*)d_in[0];
    const float* op_table  = (const float*)d_in[1];
    const float* non_table = (const float*)d_in[2];
    const float* Wm        = (const float*)d_in[3];
    const float* bm        = (const float*)d_in[4];
    const float* Wg        = (const float*)d_in[5];
    const float* bg        = (const float*)d_in[6];
    const int* ops_idx     = (const int*)d_in[7];
    const int* ents_idx    = (const int*)d_in[8];
    const int* left_idx    = (const int*)d_in[9];
    float* out = (float*)d_out;
    char* ws = (char*)d_ws;

    prep_kernel<<<3387, 256, 0, stream>>>(ent_table, op_table, non_table,
                                          Wm, bm, Wg, bg, ws, out);
    pe_kernel<<<1563, 256, 0, stream>>>(ws);
    chain_kernel<<<NROWS / 64, 512, 0, stream>>>(ent_table, ops_idx, ents_idx,
                                                 left_idx, ws, out);
}